// Round 7
// baseline (159.495 us; speedup 1.0000x reference)
//
#include <hip/hip_runtime.h>
#include <math.h>

#define OVERLAP_THRESH 0.35f
#define VALID_THRESH   0.2f
#define NEGPOS         7
#define TMAX           64
#define NCHUNK         16   // prior chunks per (b,t) argmax
#define PPT            2    // priors per thread in match_loss
#define TPW            4    // targets per wave in best_prior
#define HB             2048 // 11-bit coarse histogram buckets (u >> 20, sign bit 0)
#define CAP            12288 // LDS compact-list capacity (48 KB)

__device__ __forceinline__ float sl1(float x) {
    float ax = fabsf(x);
    return ax < 1.0f ? 0.5f * ax * ax : ax - 0.5f;
}
__device__ __forceinline__ float frcp(float x) { return __builtin_amdgcn_rcpf(x); }

// ---------------- K2: partial best-prior, split-K over priors, 4 targets/wave --------
// key = (iou_bits << 32) | (0xFFFFFFFF - p): max-key == argmax with lowest-p tie-break
__global__ void best_prior_partial_kernel(const float* __restrict__ priors,
                                          const float* __restrict__ targets,
                                          int P, int BT,
                                          unsigned long long* __restrict__ keys) {
    int wid  = blockIdx.x * (blockDim.x >> 6) + (threadIdx.x >> 6);
    int lane = threadIdx.x & 63;
    int ng    = (BT + TPW - 1) / TPW;       // target groups
    int group = wid % ng;
    int chunk = wid / ng;
    int bt0   = group * TPW;

    float tx1[TPW], ty1[TPW], tx2[TPW], ty2[TPW], ta[TPW];
    #pragma unroll
    for (int j = 0; j < TPW; j++) {
        int bt = min(bt0 + j, BT - 1);
        const float* tg = targets + (size_t)bt * 15;
        tx1[j] = tg[0]; ty1[j] = tg[1]; tx2[j] = tg[2]; ty2[j] = tg[3];
        ta[j]  = (tx2[j] - tx1[j]) * (ty2[j] - ty1[j]);
    }

    int cs = (P + NCHUNK - 1) / NCHUNK;
    int p0 = chunk * cs;
    int pend = min(p0 + cs, P);
    float best[TPW]; int bestp[TPW];
    #pragma unroll
    for (int j = 0; j < TPW; j++) { best[j] = -1.0f; bestp[j] = p0; }

    for (int p = p0 + lane; p < pend; p += 64) {
        float4 pr = ((const float4*)priors)[p];
        float hw = pr.z * 0.5f, hh = pr.w * 0.5f;
        float px1 = pr.x - hw, py1 = pr.y - hh;
        float px2 = pr.x + hw, py2 = pr.y + hh;
        float pa = (px2 - px1) * (py2 - py1);
        #pragma unroll
        for (int j = 0; j < TPW; j++) {
            float iw = fmaxf(fminf(tx2[j], px2) - fmaxf(tx1[j], px1), 0.0f);
            float ih = fmaxf(fminf(ty2[j], py2) - fmaxf(ty1[j], py1), 0.0f);
            float inter = iw * ih;
            float iou = inter * frcp(ta[j] + pa - inter);
            if (iou > best[j]) { best[j] = iou; bestp[j] = p; }  // strict >: lowest p/lane
        }
    }
    #pragma unroll
    for (int j = 0; j < TPW; j++) {
        unsigned long long key =
            ((unsigned long long)__float_as_uint(fmaxf(best[j], 0.0f)) << 32) |
            (unsigned long long)(0xFFFFFFFFu - (unsigned)bestp[j]);
        for (int off = 32; off; off >>= 1) {
            unsigned long long k2 = __shfl_down(key, off);
            if (k2 > key) key = k2;
        }
        if (lane == 0 && bt0 + j < BT) atomicMax(&keys[bt0 + j], key);
    }
}

// ---------------- K2b: unpack keys -> override map / valid bitmask / any_valid -------
__global__ void unpack_override_kernel(const unsigned long long* __restrict__ keys,
                                       int T, int BT, int P,
                                       int* __restrict__ ovr_arr,      // [B][P], 0 = none, else t+1
                                       unsigned* __restrict__ vmask,   // [B][P/32]
                                       int* __restrict__ av_arr) {     // [B]
    int i = blockIdx.x * blockDim.x + threadIdx.x;
    if (i >= BT) return;
    unsigned long long k = keys[i];
    int bpi = (int)(0xFFFFFFFFu - (unsigned)(k & 0xFFFFFFFFull));
    float iou = __uint_as_float((unsigned)(k >> 32));
    int b = i / T, t = i % T;
    atomicMax(&ovr_arr[(size_t)b * P + bpi], t + 1);   // last write wins == largest t
    if (iou >= VALID_THRESH) {
        atomicOr(&vmask[(size_t)b * (P >> 5) + (bpi >> 5)], 1u << (bpi & 31));
        atomicOr(&av_arr[b], 1);
    }
}

// ---------------- K3: per-(b,p) match + losses; 1 LDS read per truth, no ov-scan -----
__global__ void match_loss_kernel(const float* __restrict__ priors,
                                  const float* __restrict__ targets,
                                  const float* __restrict__ loc_data,
                                  const float* __restrict__ conf_data,
                                  const float* __restrict__ landm_data,
                                  const int* __restrict__ ovr_arr,
                                  const unsigned* __restrict__ vmask,
                                  const int* __restrict__ av_arr,
                                  int P, int T,
                                  float* __restrict__ rank_loss,
                                  int* __restrict__ ghist,       // [B][HB]
                                  int* __restrict__ num_pos,     // [B]
                                  int* __restrict__ total_pos1,  // [1]
                                  float* __restrict__ acc)       // [ll, llm, ce_pos, ce_neg]
{
    int b   = blockIdx.y;
    int tid = threadIdx.x;
    int p0  = (blockIdx.x * blockDim.x + tid) * PPT;

    __shared__ float4 s_box[TMAX];
    __shared__ float  s_lab[TMAX];
    __shared__ int    s_hist[HB];
    __shared__ float  s_ll, s_llm, s_cep;
    __shared__ int    s_np, s_np1;

    if (tid == 0) { s_ll = 0.f; s_llm = 0.f; s_cep = 0.f; s_np = 0; s_np1 = 0; }
    for (int i = tid; i < HB; i += blockDim.x) s_hist[i] = 0;
    if (tid < T) {
        const float* tg = targets + ((size_t)b * T + tid) * 15;
        s_box[tid] = make_float4(tg[0], tg[1], tg[2], tg[3]);
        s_lab[tid] = tg[14];
    }
    __syncthreads();
    int av = av_arr[b];

    float px1[PPT], py1[PPT], px2[PPT], py2[PPT], pa[PPT];
    float best[PPT]; int btidx[PPT];
    #pragma unroll
    for (int j = 0; j < PPT; j++) {
        int p = min(p0 + j, P - 1);
        float4 pr = ((const float4*)priors)[p];
        float hw = pr.z * 0.5f, hh = pr.w * 0.5f;
        px1[j] = pr.x - hw; py1[j] = pr.y - hh;
        px2[j] = pr.x + hw; py2[j] = pr.y + hh;
        pa[j]  = (px2[j] - px1[j]) * (py2[j] - py1[j]);
        best[j] = -1.0f; btidx[j] = 0;
    }

    // pure-IoU t-loop: 1 broadcast ds_read_b128 per t, 8 in flight
    #pragma unroll 8
    for (int t = 0; t < TMAX; t++) {
        float4 box = s_box[t];
        float ba = (box.z - box.x) * (box.w - box.y);
        #pragma unroll
        for (int j = 0; j < PPT; j++) {
            float iw = fmaxf(fminf(box.z, px2[j]) - fmaxf(box.x, px1[j]), 0.0f);
            float ih = fmaxf(fminf(box.w, py2[j]) - fmaxf(box.y, py1[j]), 0.0f);
            float inter = iw * ih;
            float iou = inter * frcp(ba + pa[j] - inter);
            if (iou > best[j]) { best[j] = iou; btidx[j] = t; }   // first occurrence
        }
    }

    // scatter overrides via precomputed map (2 coalesced loads)
    int2 ov2 = *(const int2*)&ovr_arr[(size_t)b * P + p0];
    unsigned vbits = vmask[(size_t)b * (P >> 5) + (p0 >> 5)];
    int ovr[PPT] = { ov2.x, ov2.y };

    float ll_s = 0.f, cep_s = 0.f, llm_s = 0.f;
    int np_s = 0, np1_s = 0;
    float rl[PPT];
    #pragma unroll
    for (int j = 0; j < PPT; j++) {
        int p = p0 + j;
        int bt = btidx[j];
        float bv = best[j];
        if (ovr[j] > 0) bt = ovr[j] - 1;
        if ((vbits >> ((p0 + j) & 31)) & 1u) bv = 2.0f;

        float lab = s_lab[bt];
        float conf = (av && bv >= OVERLAP_THRESH) ? lab : 0.0f;
        int   ci   = (int)conf;
        bool  pos  = (ci != 0);
        bool  pos1 = (ci > 0);

        float ce = 0.f;
        if (p < P) {
            const float* cd = conf_data + ((size_t)b * P + p) * 2;
            float c0 = cd[0], c1 = cd[1];
            float mx = fmaxf(c0, c1);
            float lse = mx + __logf(1.0f + __expf(-fabsf(c0 - c1)));
            ce = lse - (pos ? c1 : c0);
        }
        rl[j] = (pos || p >= P) ? 0.0f : fmaxf(ce, 0.0f);
        if (p < P) atomicAdd(&s_hist[__float_as_uint(rl[j]) >> 20], 1);

        if (p < P && pos) {
            float4 mb = s_box[bt];
            float pw = px2[j] - px1[j], ph = py2[j] - py1[j];
            float pcx = (px1[j] + px2[j]) * 0.5f, pcy = (py1[j] + py2[j]) * 0.5f;
            float gx = ((mb.x + mb.z) * 0.5f - pcx) * frcp(0.1f * pw);
            float gy = ((mb.y + mb.w) * 0.5f - pcy) * frcp(0.1f * ph);
            float gw = __logf((mb.z - mb.x) * frcp(pw)) * 5.0f;   // /0.2
            float gh = __logf((mb.w - mb.y) * frcp(ph)) * 5.0f;
            const float* ld = loc_data + ((size_t)b * P + p) * 4;
            ll_s += sl1(ld[0] - gx) + sl1(ld[1] - gy) + sl1(ld[2] - gw) + sl1(ld[3] - gh);
            cep_s += ce;
            np_s++;
        }
        if (p < P && pos1) {
            const float* lmd = landm_data + ((size_t)b * P + p) * 10;
            const float* lm  = targets + ((size_t)b * T + bt) * 15 + 4;
            float pw = px2[j] - px1[j], ph = py2[j] - py1[j];
            float pcx = (px1[j] + px2[j]) * 0.5f, pcy = (py1[j] + py2[j]) * 0.5f;
            float sx = frcp(0.1f * pw), sy = frcp(0.1f * ph);
            float s = 0.0f;
            #pragma unroll
            for (int k = 0; k < 5; k++) {
                float gx = (lm[2 * k]     - pcx) * sx;
                float gy = (lm[2 * k + 1] - pcy) * sy;
                s += sl1(lmd[2 * k] - gx) + sl1(lmd[2 * k + 1] - gy);
            }
            llm_s += s;
            np1_s++;
        }
    }
    if (p0 + PPT <= P) {
        *(float2*)&rank_loss[(size_t)b * P + p0] = make_float2(rl[0], rl[1]);
    } else {
        for (int j = 0; j < PPT; j++)
            if (p0 + j < P) rank_loss[(size_t)b * P + p0 + j] = rl[j];
    }

    if (np_s)  { atomicAdd(&s_ll, ll_s); atomicAdd(&s_cep, cep_s); atomicAdd(&s_np, np_s); }
    if (np1_s) { atomicAdd(&s_llm, llm_s); atomicAdd(&s_np1, np1_s); }
    __syncthreads();
    if (tid == 0) {
        if (s_np)  { atomicAdd(&num_pos[b], s_np); atomicAdd(&acc[0], s_ll); atomicAdd(&acc[2], s_cep); }
        if (s_np1) { atomicAdd(total_pos1, s_np1); atomicAdd(&acc[1], s_llm); }
    }
    // flush coarse histogram
    for (int i = tid; i < HB; i += blockDim.x) {
        int v = s_hist[i];
        if (v) atomicAdd(&ghist[(size_t)b * HB + i], v);
    }
}

// ---- single-wave digit select over nb (<=256) buckets in LDS hist ----
__device__ __forceinline__ void select_digit(const int* hist, int nb, int tid,
                                             int* s_dig, int* s_r) {
    if (tid < 64) {
        int lane = tid;
        int per  = (nb >= 64) ? (nb >> 6) : 1;
        int base = lane * per;
        int v[4]; int s = 0;
        #pragma unroll
        for (int j = 0; j < 4; j++) {
            int idx = base + j;
            int h = (j < per && idx < nb) ? hist[idx] : 0;
            v[j] = h; s += h;
        }
        int sfx = s;
        for (int off = 1; off < 64; off <<= 1) {
            int t = __shfl_down(sfx, off);
            if (lane + off < 64) sfx += t;
        }
        int r  = *s_r;
        int ge = sfx;
        #pragma unroll
        for (int j = 0; j < 4; j++) {
            int gen = ge - v[j];
            int d   = base + j;
            if (j < per && d < nb && ge >= r && gen < r) { *s_dig = d; *s_r = r - gen; }
            ge = gen;
        }
    }
}

// ---------------- K4: per-batch sum of top-K rank_loss --------------------------------
__global__ void topk_kernel(const float* __restrict__ rank_loss,
                            const int* __restrict__ num_pos,
                            const int* __restrict__ ghist,
                            int P, float* __restrict__ acc) {
    int b    = blockIdx.x;
    int tid  = threadIdx.x;
    int lane = tid & 63;
    int wv   = tid >> 6;
    long long Kll = (long long)num_pos[b] * NEGPOS;
    int K = (Kll > P - 1) ? (P - 1) : (int)Kll;
    if (K <= 0) return;

    __shared__ int   hist[256];
    __shared__ float slist[CAP];
    __shared__ int   s_d1, s_r, s_cnt1, s_lcnt, s_dig;
    __shared__ float s_S[16];
    __shared__ int   s_C[16];
    __shared__ float s_Shi;
    __shared__ int   s_Chi;

    const int* gh = ghist + (size_t)b * HB;

    // --- step A: pick coarse bucket d1 from ghist (single wave) ---
    if (wv == 0) {
        if (lane == 0) { s_lcnt = 0; s_r = K; }
        int base = lane * 32;
        int v[32]; int s = 0;
        #pragma unroll
        for (int j = 0; j < 32; j++) { v[j] = gh[base + j]; s += v[j]; }
        int sfx = s;
        for (int off = 1; off < 64; off <<= 1) {
            int t = __shfl_down(sfx, off);
            if (lane + off < 64) sfx += t;
        }
        int ge = sfx;
        #pragma unroll
        for (int j = 0; j < 32; j++) {
            int gen = ge - v[j];
            if (ge >= K && gen < K) { s_d1 = base + j; s_r = K - gen; s_cnt1 = v[j]; }
            ge = gen;
        }
    }
    __syncthreads();
    int d1 = s_d1, cnt1 = s_cnt1;
    bool fastpath = (cnt1 <= CAP);
    unsigned hi_lim = ((unsigned)(d1 + 1)) << 20;

    const float4* v4 = (const float4*)(rank_loss + (size_t)b * P);
    int n4 = P >> 2;
    unsigned pmask = 0u, pval = 0u;
    const int shf[3] = {12, 4, 0};
    const int nbk[3] = {256, 256, 16};

    if (fastpath) {
        float Shi = 0.f; int Chi = 0;
        for (int i = tid; i < n4; i += blockDim.x) {
            float4 x = v4[i];
            float xs[4] = {x.x, x.y, x.z, x.w};
            #pragma unroll
            for (int k = 0; k < 4; k++) {
                unsigned u = __float_as_uint(xs[k]);
                if (u >= hi_lim) { Shi += xs[k]; Chi++; }
                bool m = ((u >> 20) == (unsigned)d1);
                unsigned long long mk = __ballot(m);
                if (m) {
                    int leader = __ffsll((long long)mk) - 1;
                    int base = 0;
                    if (lane == leader) base = atomicAdd(&s_lcnt, __popcll(mk));
                    base = __shfl(base, leader);
                    int ofs = __popcll(mk & (((unsigned long long)1 << lane) - 1ull));
                    slist[base + ofs] = xs[k];
                }
            }
        }
        for (int off = 32; off; off >>= 1) {
            Shi += __shfl_down(Shi, off);
            Chi += __shfl_down(Chi, off);
        }
        if (lane == 0) { s_S[wv] = Shi; s_C[wv] = Chi; }
        __syncthreads();
        if (tid == 0) {
            float S = 0.f; int C = 0;
            for (int i = 0; i < 16; i++) { S += s_S[i]; C += s_C[i]; }
            s_Shi = S; s_Chi = C;
        }
        __syncthreads();
        int lc = s_lcnt;

        for (int ps = 0; ps < 3; ps++) {
            int sh = shf[ps]; unsigned wm = (unsigned)(nbk[ps] - 1);
            if (tid < 256) hist[tid] = 0;
            __syncthreads();
            for (int i = tid; i < lc; i += blockDim.x) {
                unsigned u = __float_as_uint(slist[i]);
                if ((u & pmask) == pval) atomicAdd(&hist[(u >> sh) & wm], 1);
            }
            __syncthreads();
            select_digit(hist, nbk[ps], tid, &s_dig, &s_r);
            __syncthreads();
            pval  |= ((unsigned)s_dig) << sh;
            pmask |= wm << sh;
        }
        float tau = __uint_as_float((((unsigned)d1) << 20) | pval);

        float S = 0.f; int C = 0;
        for (int i = tid; i < lc; i += blockDim.x) {
            float x = slist[i];
            if (x > tau) { S += x; C++; }
        }
        for (int off = 32; off; off >>= 1) {
            S += __shfl_down(S, off);
            C += __shfl_down(C, off);
        }
        if (lane == 0) { s_S[wv] = S; s_C[wv] = C; }
        __syncthreads();
        if (tid == 0) {
            float St = s_Shi; int Ct = s_Chi;
            for (int i = 0; i < 16; i++) { St += s_S[i]; Ct += s_C[i]; }
            atomicAdd(&acc[3], St + (float)(K - Ct) * tau);
        }
    } else {
        for (int ps = 0; ps < 3; ps++) {
            int sh = shf[ps]; unsigned wm = (unsigned)(nbk[ps] - 1);
            if (tid < 256) hist[tid] = 0;
            __syncthreads();
            for (int i = tid; i < n4; i += blockDim.x) {
                float4 x = v4[i];
                float xs[4] = {x.x, x.y, x.z, x.w};
                #pragma unroll
                for (int k = 0; k < 4; k++) {
                    unsigned u = __float_as_uint(xs[k]);
                    if ((u >> 20) == (unsigned)d1 && (u & pmask) == pval)
                        atomicAdd(&hist[(u >> sh) & wm], 1);
                }
            }
            __syncthreads();
            select_digit(hist, nbk[ps], tid, &s_dig, &s_r);
            __syncthreads();
            pval  |= ((unsigned)s_dig) << sh;
            pmask |= wm << sh;
        }
        float tau = __uint_as_float((((unsigned)d1) << 20) | pval);
        float S = 0.f; int C = 0;
        for (int i = tid; i < n4; i += blockDim.x) {
            float4 x = v4[i];
            float xs[4] = {x.x, x.y, x.z, x.w};
            #pragma unroll
            for (int k = 0; k < 4; k++)
                if (xs[k] > tau) { S += xs[k]; C++; }
        }
        for (int off = 32; off; off >>= 1) {
            S += __shfl_down(S, off);
            C += __shfl_down(C, off);
        }
        if (lane == 0) { s_S[wv] = S; s_C[wv] = C; }
        __syncthreads();
        if (tid == 0) {
            float St = 0.f; int Ct = 0;
            for (int i = 0; i < 16; i++) { St += s_S[i]; Ct += s_C[i]; }
            atomicAdd(&acc[3], St + (float)(K - Ct) * tau);
        }
    }
}

// ---------------- K5: finalize -------------------------------------------------------
__global__ void finalize_kernel(const int* __restrict__ num_pos,
                                const int* __restrict__ total_pos1,
                                const float* __restrict__ acc,
                                int B, float* __restrict__ out) {
    int tp = 0;
    for (int b = 0; b < B; b++) tp += num_pos[b];
    float N  = fmaxf((float)tp, 1.0f);
    float N1 = fmaxf((float)(*total_pos1), 1.0f);
    out[0] = acc[0] / N;                 // loss_l / N
    out[1] = (acc[2] + acc[3]) / N;      // loss_c / N
    out[2] = acc[1] / N1;                // loss_landm / N1
}

extern "C" void kernel_launch(void* const* d_in, const int* in_sizes, int n_in,
                              void* d_out, int out_size, void* d_ws, size_t ws_size,
                              hipStream_t stream) {
    const float* loc_data   = (const float*)d_in[0];
    const float* conf_data  = (const float*)d_in[1];
    const float* landm_data = (const float*)d_in[2];
    const float* priors     = (const float*)d_in[3];
    const float* targets    = (const float*)d_in[4];
    float* out = (float*)d_out;

    int P  = in_sizes[3] / 4;
    int BP = in_sizes[0] / 4;
    int B  = BP / P;
    int T  = in_sizes[4] / (B * 15);
    int BT = B * T;

    char* ws = (char*)d_ws;
    float* rank_loss = (float*)ws;
    size_t off = (size_t)B * P * sizeof(float);
    // zeroed region starts here
    int* ovr_arr    = (int*)(ws + off); off += (size_t)B * P * sizeof(int);
    unsigned* vmask = (unsigned*)(ws + off); off += (size_t)B * (P >> 5) * sizeof(unsigned);
    int* ghist      = (int*)(ws + off); off += (size_t)B * HB * sizeof(int);
    unsigned long long* keys = (unsigned long long*)(ws + off); off += (size_t)BT * sizeof(unsigned long long);
    int* av_arr     = (int*)(ws + off); off += (size_t)B * sizeof(int);
    int* num_pos    = (int*)(ws + off); off += (size_t)B * sizeof(int);
    int* total_pos1 = (int*)(ws + off); off += sizeof(int);
    float* acc      = (float*)(ws + off); off += 4 * sizeof(float);

    size_t zbytes = (size_t)((char*)(acc + 4) - (char*)ovr_arr);
    hipMemsetAsync(ovr_arr, 0, zbytes, stream);

    // K2: split-K best-prior, 4 targets per wave.
    int waves   = NCHUNK * ((BT + TPW - 1) / TPW);
    int blocks2 = (waves + 3) / 4;
    best_prior_partial_kernel<<<blocks2, 256, 0, stream>>>(priors, targets, P, BT, keys);

    // K2b: unpack scatter-override map.
    unpack_override_kernel<<<(BT + 255) / 256, 256, 0, stream>>>(keys, T, BT, P,
                                                                 ovr_arr, vmask, av_arr);

    // K3: match + per-prior losses + coarse rank_loss histogram.
    dim3 g3((P + 256 * PPT - 1) / (256 * PPT), B);
    match_loss_kernel<<<g3, 256, 0, stream>>>(priors, targets, loc_data, conf_data,
                                              landm_data, ovr_arr, vmask, av_arr, P, T,
                                              rank_loss, ghist, num_pos, total_pos1, acc);

    // K4: top-K sum, one full scan + LDS-local refinement.
    topk_kernel<<<B, 1024, 0, stream>>>(rank_loss, num_pos, ghist, P, acc);

    finalize_kernel<<<1, 1, 0, stream>>>(num_pos, total_pos1, acc, B, out);
}

// Round 8
// 156.565 us; speedup vs baseline: 1.0187x; 1.0187x over previous
//
#include <hip/hip_runtime.h>
#include <math.h>

#define OVERLAP_THRESH 0.35f
#define VALID_THRESH   0.2f
#define NEGPOS         7
#define TMAX           64
#define NCHUNK         16   // prior chunks per (b,t) argmax
#define PPT            4    // priors per thread in iou_scan
#define TPW            4    // targets per wave in best_prior
#define HB             2048 // 11-bit coarse histogram buckets (u >> 20, sign bit 0)
#define CAP            12288 // LDS compact-list capacity (48 KB)

__device__ __forceinline__ float sl1(float x) {
    float ax = fabsf(x);
    return ax < 1.0f ? 0.5f * ax * ax : ax - 0.5f;
}
__device__ __forceinline__ float frcp(float x) { return __builtin_amdgcn_rcpf(x); }

// ---------------- K2: partial best-prior, split-K over priors, 4 targets/wave --------
// key = (iou_bits << 32) | (0xFFFFFFFF - p): max-key == argmax with lowest-p tie-break
__global__ void best_prior_partial_kernel(const float* __restrict__ priors,
                                          const float* __restrict__ targets,
                                          int P, int BT,
                                          unsigned long long* __restrict__ keys) {
    int wid  = blockIdx.x * (blockDim.x >> 6) + (threadIdx.x >> 6);
    int lane = threadIdx.x & 63;
    int ng    = (BT + TPW - 1) / TPW;       // target groups
    int group = wid % ng;
    int chunk = wid / ng;
    int bt0   = group * TPW;

    float tx1[TPW], ty1[TPW], tx2[TPW], ty2[TPW], ta[TPW];
    #pragma unroll
    for (int j = 0; j < TPW; j++) {
        int bt = min(bt0 + j, BT - 1);
        const float* tg = targets + (size_t)bt * 15;
        tx1[j] = tg[0]; ty1[j] = tg[1]; tx2[j] = tg[2]; ty2[j] = tg[3];
        ta[j]  = (tx2[j] - tx1[j]) * (ty2[j] - ty1[j]);
    }

    int cs = (P + NCHUNK - 1) / NCHUNK;
    int p0 = chunk * cs;
    int pend = min(p0 + cs, P);
    float best[TPW]; int bestp[TPW];
    #pragma unroll
    for (int j = 0; j < TPW; j++) { best[j] = -1.0f; bestp[j] = p0; }

    for (int p = p0 + lane; p < pend; p += 64) {
        float4 pr = ((const float4*)priors)[p];
        float hw = pr.z * 0.5f, hh = pr.w * 0.5f;
        float px1 = pr.x - hw, py1 = pr.y - hh;
        float px2 = pr.x + hw, py2 = pr.y + hh;
        float pa = (px2 - px1) * (py2 - py1);
        #pragma unroll
        for (int j = 0; j < TPW; j++) {
            float iw = fmaxf(fminf(tx2[j], px2) - fmaxf(tx1[j], px1), 0.0f);
            float ih = fmaxf(fminf(ty2[j], py2) - fmaxf(ty1[j], py1), 0.0f);
            float inter = iw * ih;
            float iou = inter * frcp(ta[j] + pa - inter);
            if (iou > best[j]) { best[j] = iou; bestp[j] = p; }  // strict >: lowest p/lane
        }
    }
    #pragma unroll
    for (int j = 0; j < TPW; j++) {
        unsigned long long key =
            ((unsigned long long)__float_as_uint(fmaxf(best[j], 0.0f)) << 32) |
            (unsigned long long)(0xFFFFFFFFu - (unsigned)bestp[j]);
        for (int off = 32; off; off >>= 1) {
            unsigned long long k2 = __shfl_down(key, off);
            if (k2 > key) key = k2;
        }
        if (lane == 0 && bt0 + j < BT) atomicMax(&keys[bt0 + j], key);
    }
}

// ---------------- K2b: unpack keys -> override map / valid bitmask / any_valid -------
__global__ void unpack_override_kernel(const unsigned long long* __restrict__ keys,
                                       int T, int BT, int P,
                                       int* __restrict__ ovr_arr,      // [B][P], 0 = none, else t+1
                                       unsigned* __restrict__ vmask,   // [B][P/32]
                                       int* __restrict__ av_arr) {     // [B]
    int i = blockIdx.x * blockDim.x + threadIdx.x;
    if (i >= BT) return;
    unsigned long long k = keys[i];
    int bpi = (int)(0xFFFFFFFFu - (unsigned)(k & 0xFFFFFFFFull));
    float iou = __uint_as_float((unsigned)(k >> 32));
    int b = i / T, t = i % T;
    atomicMax(&ovr_arr[(size_t)b * P + bpi], t + 1);   // last write wins == largest t
    if (iou >= VALID_THRESH) {
        atomicOr(&vmask[(size_t)b * (P >> 5) + (bpi >> 5)], 1u << (bpi & 31));
        atomicOr(&av_arr[b], 1);
    }
}

// ---------------- K3a: pure IoU argmax over T truths, PPT priors/thread --------------
// No atomics, no hist, no reductions: writes best-iou (f32) + best-t (u8) per prior.
__global__ void iou_scan_kernel(const float* __restrict__ priors,
                                const float* __restrict__ targets,
                                int P, int T,
                                float* __restrict__ biou,
                                unsigned char* __restrict__ bt8) {
    int b   = blockIdx.y;
    int tid = threadIdx.x;
    int p0  = (blockIdx.x * blockDim.x + tid) * PPT;

    __shared__ float4 s_box[TMAX];
    __shared__ float  s_ba[TMAX];
    if (tid < T) {
        const float* tg = targets + ((size_t)b * T + tid) * 15;
        float x1 = tg[0], y1 = tg[1], x2 = tg[2], y2 = tg[3];
        s_box[tid] = make_float4(x1, y1, x2, y2);
        s_ba[tid]  = (x2 - x1) * (y2 - y1);
    }
    __syncthreads();

    float px1[PPT], py1[PPT], px2[PPT], py2[PPT], pa[PPT];
    float best[PPT]; int btidx[PPT];
    #pragma unroll
    for (int j = 0; j < PPT; j++) {
        int p = min(p0 + j, P - 1);
        float4 pr = ((const float4*)priors)[p];
        float hw = pr.z * 0.5f, hh = pr.w * 0.5f;
        px1[j] = pr.x - hw; py1[j] = pr.y - hh;
        px2[j] = pr.x + hw; py2[j] = pr.y + hh;
        pa[j]  = (px2[j] - px1[j]) * (py2[j] - py1[j]);
        best[j] = -1.0f; btidx[j] = 0;
    }

    #pragma unroll 8
    for (int t = 0; t < T; t++) {
        float4 box = s_box[t];
        float  ba  = s_ba[t];
        #pragma unroll
        for (int j = 0; j < PPT; j++) {
            float iw = fmaxf(fminf(box.z, px2[j]) - fmaxf(box.x, px1[j]), 0.0f);
            float ih = fmaxf(fminf(box.w, py2[j]) - fmaxf(box.y, py1[j]), 0.0f);
            float inter = iw * ih;
            float iou = inter * frcp(ba + pa[j] - inter);
            if (iou > best[j]) { best[j] = iou; btidx[j] = t; }   // first occurrence
        }
    }

    if (p0 + PPT <= P) {
        *(float4*)&biou[(size_t)b * P + p0] = make_float4(best[0], best[1], best[2], best[3]);
        uchar4 bt4 = make_uchar4((unsigned char)btidx[0], (unsigned char)btidx[1],
                                 (unsigned char)btidx[2], (unsigned char)btidx[3]);
        *(uchar4*)&bt8[(size_t)b * P + p0] = bt4;
    } else {
        for (int j = 0; j < PPT; j++)
            if (p0 + j < P) {
                biou[(size_t)b * P + p0 + j] = best[j];
                bt8[(size_t)b * P + p0 + j] = (unsigned char)btidx[j];
            }
    }
}

// ---------------- K3b: streaming loss eval, 1 prior/thread, per-batch accumulators ---
__global__ void loss_eval_kernel(const float* __restrict__ priors,
                                 const float* __restrict__ targets,
                                 const float* __restrict__ loc_data,
                                 const float* __restrict__ conf_data,
                                 const float* __restrict__ landm_data,
                                 const float* __restrict__ biou,
                                 const unsigned char* __restrict__ bt8,
                                 const int* __restrict__ ovr_arr,
                                 const unsigned* __restrict__ vmask,
                                 const int* __restrict__ av_arr,
                                 int P, int T,
                                 float* __restrict__ rank_loss,
                                 int* __restrict__ ghist,      // [B][HB]
                                 int* __restrict__ num_pos,    // [B]
                                 int* __restrict__ num_pos1,   // [B]
                                 float* __restrict__ accb)     // [B][3]: ll, llm, ce_pos
{
    int b   = blockIdx.y;
    int tid = threadIdx.x;
    int p   = blockIdx.x * blockDim.x + tid;
    size_t idx = (size_t)b * P + p;

    __shared__ int   s_hist[HB];
    __shared__ float s_ll, s_llm, s_cep;
    __shared__ int   s_np, s_np1;

    if (tid == 0) { s_ll = 0.f; s_llm = 0.f; s_cep = 0.f; s_np = 0; s_np1 = 0; }
    for (int i = tid; i < HB; i += blockDim.x) s_hist[i] = 0;
    __syncthreads();

    if (p < P) {
        int   bt = bt8[idx];
        float bv = biou[idx];
        int   ov = ovr_arr[idx];
        if (ov > 0) bt = ov - 1;
        unsigned vb = vmask[(size_t)b * (P >> 5) + (p >> 5)];
        if ((vb >> (p & 31)) & 1u) bv = 2.0f;
        int av = av_arr[b];

        bool cond = (av && bv >= OVERLAP_THRESH);
        const float* tg = targets + ((size_t)b * T + bt) * 15;
        float lab  = cond ? tg[14] : 0.0f;     // label gather only when matched
        int   ci   = (int)lab;                 // conf = cond ? lab : 0; astype(int32)
        bool  pos  = cond && (ci != 0);
        bool  pos1 = cond && (ci > 0);

        const float* cd = conf_data + idx * 2;
        float c0 = cd[0], c1 = cd[1];
        float mx = fmaxf(c0, c1);
        float lse = mx + __logf(1.0f + __expf(-fabsf(c0 - c1)));
        float ce  = lse - (pos ? c1 : c0);
        float rl  = pos ? 0.0f : fmaxf(ce, 0.0f);
        rank_loss[idx] = rl;
        atomicAdd(&s_hist[__float_as_uint(rl) >> 20], 1);

        if (pos) {
            float4 pr = ((const float4*)priors)[p];
            float pw = pr.z, ph = pr.w;
            float mbx1 = tg[0], mby1 = tg[1], mbx2 = tg[2], mby2 = tg[3];
            float gx = ((mbx1 + mbx2) * 0.5f - pr.x) * frcp(0.1f * pw);
            float gy = ((mby1 + mby2) * 0.5f - pr.y) * frcp(0.1f * ph);
            float gw = __logf((mbx2 - mbx1) * frcp(pw)) * 5.0f;   // /0.2
            float gh = __logf((mby2 - mby1) * frcp(ph)) * 5.0f;
            const float* ld = loc_data + idx * 4;
            float ll = sl1(ld[0] - gx) + sl1(ld[1] - gy) + sl1(ld[2] - gw) + sl1(ld[3] - gh);
            atomicAdd(&s_ll, ll);
            atomicAdd(&s_cep, ce);
            atomicAdd(&s_np, 1);
        }
        if (pos1) {
            float4 pr = ((const float4*)priors)[p];
            const float* lmd = landm_data + idx * 10;
            const float* lm  = tg + 4;
            float sx = frcp(0.1f * pr.z), sy = frcp(0.1f * pr.w);
            float s = 0.0f;
            #pragma unroll
            for (int k = 0; k < 5; k++) {
                float gx = (lm[2 * k]     - pr.x) * sx;
                float gy = (lm[2 * k + 1] - pr.y) * sy;
                s += sl1(lmd[2 * k] - gx) + sl1(lmd[2 * k + 1] - gy);
            }
            atomicAdd(&s_llm, s);
            atomicAdd(&s_np1, 1);
        }
    }
    __syncthreads();
    if (tid == 0) {
        if (s_np)  { atomicAdd(&num_pos[b], s_np);
                     atomicAdd(&accb[b * 3 + 0], s_ll);
                     atomicAdd(&accb[b * 3 + 2], s_cep); }
        if (s_np1) { atomicAdd(&num_pos1[b], s_np1);
                     atomicAdd(&accb[b * 3 + 1], s_llm); }
    }
    for (int i = tid; i < HB; i += blockDim.x) {
        int v = s_hist[i];
        if (v) atomicAdd(&ghist[(size_t)b * HB + i], v);
    }
}

// ---- single-wave digit select over nb (<=256) buckets in LDS hist ----
__device__ __forceinline__ void select_digit(const int* hist, int nb, int tid,
                                             int* s_dig, int* s_r) {
    if (tid < 64) {
        int lane = tid;
        int per  = (nb >= 64) ? (nb >> 6) : 1;
        int base = lane * per;
        int v[4]; int s = 0;
        #pragma unroll
        for (int j = 0; j < 4; j++) {
            int idx = base + j;
            int h = (j < per && idx < nb) ? hist[idx] : 0;
            v[j] = h; s += h;
        }
        int sfx = s;
        for (int off = 1; off < 64; off <<= 1) {
            int t = __shfl_down(sfx, off);
            if (lane + off < 64) sfx += t;
        }
        int r  = *s_r;
        int ge = sfx;
        #pragma unroll
        for (int j = 0; j < 4; j++) {
            int gen = ge - v[j];
            int d   = base + j;
            if (j < per && d < nb && ge >= r && gen < r) { *s_dig = d; *s_r = r - gen; }
            ge = gen;
        }
    }
}

// ---------------- K4: per-batch sum of top-K rank_loss --------------------------------
__global__ void topk_kernel(const float* __restrict__ rank_loss,
                            const int* __restrict__ num_pos,
                            const int* __restrict__ ghist,
                            int P, float* __restrict__ accn) {   // [B]
    int b    = blockIdx.x;
    int tid  = threadIdx.x;
    int lane = tid & 63;
    int wv   = tid >> 6;
    long long Kll = (long long)num_pos[b] * NEGPOS;
    int K = (Kll > P - 1) ? (P - 1) : (int)Kll;
    if (K <= 0) return;

    __shared__ int   hist[256];
    __shared__ float slist[CAP];
    __shared__ int   s_d1, s_r, s_cnt1, s_lcnt, s_dig;
    __shared__ float s_S[16];
    __shared__ int   s_C[16];
    __shared__ float s_Shi;
    __shared__ int   s_Chi;

    const int* gh = ghist + (size_t)b * HB;

    if (wv == 0) {
        if (lane == 0) { s_lcnt = 0; s_r = K; }
        int base = lane * 32;
        int v[32]; int s = 0;
        #pragma unroll
        for (int j = 0; j < 32; j++) { v[j] = gh[base + j]; s += v[j]; }
        int sfx = s;
        for (int off = 1; off < 64; off <<= 1) {
            int t = __shfl_down(sfx, off);
            if (lane + off < 64) sfx += t;
        }
        int ge = sfx;
        #pragma unroll
        for (int j = 0; j < 32; j++) {
            int gen = ge - v[j];
            if (ge >= K && gen < K) { s_d1 = base + j; s_r = K - gen; s_cnt1 = v[j]; }
            ge = gen;
        }
    }
    __syncthreads();
    int d1 = s_d1, cnt1 = s_cnt1;
    bool fastpath = (cnt1 <= CAP);
    unsigned hi_lim = ((unsigned)(d1 + 1)) << 20;

    const float4* v4 = (const float4*)(rank_loss + (size_t)b * P);
    int n4 = P >> 2;
    unsigned pmask = 0u, pval = 0u;
    const int shf[3] = {12, 4, 0};
    const int nbk[3] = {256, 256, 16};

    if (fastpath) {
        float Shi = 0.f; int Chi = 0;
        for (int i = tid; i < n4; i += blockDim.x) {
            float4 x = v4[i];
            float xs[4] = {x.x, x.y, x.z, x.w};
            #pragma unroll
            for (int k = 0; k < 4; k++) {
                unsigned u = __float_as_uint(xs[k]);
                if (u >= hi_lim) { Shi += xs[k]; Chi++; }
                bool m = ((u >> 20) == (unsigned)d1);
                unsigned long long mk = __ballot(m);
                if (m) {
                    int leader = __ffsll((long long)mk) - 1;
                    int base = 0;
                    if (lane == leader) base = atomicAdd(&s_lcnt, __popcll(mk));
                    base = __shfl(base, leader);
                    int ofs = __popcll(mk & (((unsigned long long)1 << lane) - 1ull));
                    slist[base + ofs] = xs[k];
                }
            }
        }
        for (int off = 32; off; off >>= 1) {
            Shi += __shfl_down(Shi, off);
            Chi += __shfl_down(Chi, off);
        }
        if (lane == 0) { s_S[wv] = Shi; s_C[wv] = Chi; }
        __syncthreads();
        if (tid == 0) {
            float S = 0.f; int C = 0;
            for (int i = 0; i < 16; i++) { S += s_S[i]; C += s_C[i]; }
            s_Shi = S; s_Chi = C;
        }
        __syncthreads();
        int lc = s_lcnt;

        for (int ps = 0; ps < 3; ps++) {
            int sh = shf[ps]; unsigned wm = (unsigned)(nbk[ps] - 1);
            if (tid < 256) hist[tid] = 0;
            __syncthreads();
            for (int i = tid; i < lc; i += blockDim.x) {
                unsigned u = __float_as_uint(slist[i]);
                if ((u & pmask) == pval) atomicAdd(&hist[(u >> sh) & wm], 1);
            }
            __syncthreads();
            select_digit(hist, nbk[ps], tid, &s_dig, &s_r);
            __syncthreads();
            pval  |= ((unsigned)s_dig) << sh;
            pmask |= wm << sh;
        }
        float tau = __uint_as_float((((unsigned)d1) << 20) | pval);

        float S = 0.f; int C = 0;
        for (int i = tid; i < lc; i += blockDim.x) {
            float x = slist[i];
            if (x > tau) { S += x; C++; }
        }
        for (int off = 32; off; off >>= 1) {
            S += __shfl_down(S, off);
            C += __shfl_down(C, off);
        }
        if (lane == 0) { s_S[wv] = S; s_C[wv] = C; }
        __syncthreads();
        if (tid == 0) {
            float St = s_Shi; int Ct = s_Chi;
            for (int i = 0; i < 16; i++) { St += s_S[i]; Ct += s_C[i]; }
            accn[b] = St + (float)(K - Ct) * tau;     // single writer per b
        }
    } else {
        for (int ps = 0; ps < 3; ps++) {
            int sh = shf[ps]; unsigned wm = (unsigned)(nbk[ps] - 1);
            if (tid < 256) hist[tid] = 0;
            __syncthreads();
            for (int i = tid; i < n4; i += blockDim.x) {
                float4 x = v4[i];
                float xs[4] = {x.x, x.y, x.z, x.w};
                #pragma unroll
                for (int k = 0; k < 4; k++) {
                    unsigned u = __float_as_uint(xs[k]);
                    if ((u >> 20) == (unsigned)d1 && (u & pmask) == pval)
                        atomicAdd(&hist[(u >> sh) & wm], 1);
                }
            }
            __syncthreads();
            select_digit(hist, nbk[ps], tid, &s_dig, &s_r);
            __syncthreads();
            pval  |= ((unsigned)s_dig) << sh;
            pmask |= wm << sh;
        }
        float tau = __uint_as_float((((unsigned)d1) << 20) | pval);
        float S = 0.f; int C = 0;
        for (int i = tid; i < n4; i += blockDim.x) {
            float4 x = v4[i];
            float xs[4] = {x.x, x.y, x.z, x.w};
            #pragma unroll
            for (int k = 0; k < 4; k++)
                if (xs[k] > tau) { S += xs[k]; C++; }
        }
        for (int off = 32; off; off >>= 1) {
            S += __shfl_down(S, off);
            C += __shfl_down(C, off);
        }
        if (lane == 0) { s_S[wv] = S; s_C[wv] = C; }
        __syncthreads();
        if (tid == 0) {
            float St = 0.f; int Ct = 0;
            for (int i = 0; i < 16; i++) { St += s_S[i]; Ct += s_C[i]; }
            accn[b] = St + (float)(K - Ct) * tau;
        }
    }
}

// ---------------- K5: finalize -------------------------------------------------------
__global__ void finalize_kernel(const int* __restrict__ num_pos,
                                const int* __restrict__ num_pos1,
                                const float* __restrict__ accb,
                                const float* __restrict__ accn,
                                int B, float* __restrict__ out) {
    int tp = 0, tp1 = 0;
    float ll = 0.f, llm = 0.f, cep = 0.f, cen = 0.f;
    for (int b = 0; b < B; b++) {
        tp  += num_pos[b];
        tp1 += num_pos1[b];
        ll  += accb[b * 3 + 0];
        llm += accb[b * 3 + 1];
        cep += accb[b * 3 + 2];
        cen += accn[b];
    }
    float N  = fmaxf((float)tp, 1.0f);
    float N1 = fmaxf((float)tp1, 1.0f);
    out[0] = ll / N;
    out[1] = (cep + cen) / N;
    out[2] = llm / N1;
}

extern "C" void kernel_launch(void* const* d_in, const int* in_sizes, int n_in,
                              void* d_out, int out_size, void* d_ws, size_t ws_size,
                              hipStream_t stream) {
    const float* loc_data   = (const float*)d_in[0];
    const float* conf_data  = (const float*)d_in[1];
    const float* landm_data = (const float*)d_in[2];
    const float* priors     = (const float*)d_in[3];
    const float* targets    = (const float*)d_in[4];
    float* out = (float*)d_out;

    int P  = in_sizes[3] / 4;
    int BP = in_sizes[0] / 4;
    int B  = BP / P;
    int T  = in_sizes[4] / (B * 15);
    int BT = B * T;

    char* ws = (char*)d_ws;
    float* rank_loss = (float*)ws;                    size_t off = (size_t)B * P * sizeof(float);
    float* biou      = (float*)(ws + off);            off += (size_t)B * P * sizeof(float);
    unsigned char* bt8 = (unsigned char*)(ws + off);  off += (size_t)B * P;
    // zeroed region starts here
    int* ovr_arr    = (int*)(ws + off);      off += (size_t)B * P * sizeof(int);
    unsigned* vmask = (unsigned*)(ws + off); off += (size_t)B * (P >> 5) * sizeof(unsigned);
    int* ghist      = (int*)(ws + off);      off += (size_t)B * HB * sizeof(int);
    unsigned long long* keys = (unsigned long long*)(ws + off); off += (size_t)BT * sizeof(unsigned long long);
    int* av_arr     = (int*)(ws + off);      off += (size_t)B * sizeof(int);
    int* num_pos    = (int*)(ws + off);      off += (size_t)B * sizeof(int);
    int* num_pos1   = (int*)(ws + off);      off += (size_t)B * sizeof(int);
    float* accb     = (float*)(ws + off);    off += (size_t)B * 3 * sizeof(float);
    float* accn     = (float*)(ws + off);    off += (size_t)B * sizeof(float);

    size_t zbytes = (size_t)((char*)(accn + B) - (char*)ovr_arr);
    hipMemsetAsync(ovr_arr, 0, zbytes, stream);

    // K2: split-K best-prior, 4 targets per wave.
    int waves   = NCHUNK * ((BT + TPW - 1) / TPW);
    int blocks2 = (waves + 3) / 4;
    best_prior_partial_kernel<<<blocks2, 256, 0, stream>>>(priors, targets, P, BT, keys);

    // K2b: unpack scatter-override map.
    unpack_override_kernel<<<(BT + 255) / 256, 256, 0, stream>>>(keys, T, BT, P,
                                                                 ovr_arr, vmask, av_arr);

    // K3a: pure IoU argmax.
    dim3 ga((P + 256 * PPT - 1) / (256 * PPT), B);
    iou_scan_kernel<<<ga, 256, 0, stream>>>(priors, targets, P, T, biou, bt8);

    // K3b: streaming loss evaluation + coarse histogram.
    dim3 gb((P + 255) / 256, B);
    loss_eval_kernel<<<gb, 256, 0, stream>>>(priors, targets, loc_data, conf_data,
                                             landm_data, biou, bt8, ovr_arr, vmask, av_arr,
                                             P, T, rank_loss, ghist, num_pos, num_pos1, accb);

    // K4: top-K sum, one full scan + LDS-local refinement.
    topk_kernel<<<B, 1024, 0, stream>>>(rank_loss, num_pos, ghist, P, accn);

    finalize_kernel<<<1, 1, 0, stream>>>(num_pos, num_pos1, accb, accn, B, out);
}

// Round 9
// 133.381 us; speedup vs baseline: 1.1958x; 1.1738x over previous
//
#include <hip/hip_runtime.h>
#include <math.h>

#define OVERLAP_THRESH 0.35f
#define VALID_THRESH   0.2f
#define NEGPOS         7
#define TMAX           64
#define NCHUNK         16   // prior chunks per (b,t) argmax
#define PPT            4    // priors per thread in iou_scan
#define TPW            4    // targets per wave in best_prior
#define EPT            4    // elements per thread in loss_eval
#define HB             2048 // 11-bit coarse histogram buckets (u >> 20, sign bit 0)
#define NC             4    // LDS hist copies (contention spread)
#define CAP            12288 // LDS compact-list capacity (48 KB)

__device__ __forceinline__ float sl1(float x) {
    float ax = fabsf(x);
    return ax < 1.0f ? 0.5f * ax * ax : ax - 0.5f;
}
__device__ __forceinline__ float frcp(float x) { return __builtin_amdgcn_rcpf(x); }

__device__ __forceinline__ void atomicMaxU8(unsigned char* addr, unsigned char val) {
    size_t a = (size_t)addr;
    unsigned* word = (unsigned*)(a & ~(size_t)3);
    int shift = (int)(a & 3) * 8;
    unsigned old = *word, assumed;
    do {
        unsigned cur = (old >> shift) & 0xFFu;
        if (cur >= val) break;
        assumed = old;
        unsigned nw = (old & ~(0xFFu << shift)) | ((unsigned)val << shift);
        old = atomicCAS(word, assumed, nw);
    } while (old != assumed);
}

// ---------------- K2: partial best-prior, split-K over priors, 4 targets/wave --------
// key = (iou_bits << 32) | (0xFFFFFFFF - p): max-key == argmax with lowest-p tie-break
__global__ void best_prior_partial_kernel(const float* __restrict__ priors,
                                          const float* __restrict__ targets,
                                          int P, int BT,
                                          unsigned long long* __restrict__ keys) {
    int wid  = blockIdx.x * (blockDim.x >> 6) + (threadIdx.x >> 6);
    int lane = threadIdx.x & 63;
    int ng    = (BT + TPW - 1) / TPW;       // target groups
    int group = wid % ng;
    int chunk = wid / ng;
    int bt0   = group * TPW;

    float tx1[TPW], ty1[TPW], tx2[TPW], ty2[TPW], ta[TPW];
    #pragma unroll
    for (int j = 0; j < TPW; j++) {
        int bt = min(bt0 + j, BT - 1);
        const float* tg = targets + (size_t)bt * 15;
        tx1[j] = tg[0]; ty1[j] = tg[1]; tx2[j] = tg[2]; ty2[j] = tg[3];
        ta[j]  = (tx2[j] - tx1[j]) * (ty2[j] - ty1[j]);
    }

    int cs = (P + NCHUNK - 1) / NCHUNK;
    int p0 = chunk * cs;
    int pend = min(p0 + cs, P);
    float best[TPW]; int bestp[TPW];
    #pragma unroll
    for (int j = 0; j < TPW; j++) { best[j] = -1.0f; bestp[j] = p0; }

    for (int p = p0 + lane; p < pend; p += 64) {
        float4 pr = ((const float4*)priors)[p];
        float hw = pr.z * 0.5f, hh = pr.w * 0.5f;
        float px1 = pr.x - hw, py1 = pr.y - hh;
        float px2 = pr.x + hw, py2 = pr.y + hh;
        float pa = (px2 - px1) * (py2 - py1);
        #pragma unroll
        for (int j = 0; j < TPW; j++) {
            float iw = fmaxf(fminf(tx2[j], px2) - fmaxf(tx1[j], px1), 0.0f);
            float ih = fmaxf(fminf(ty2[j], py2) - fmaxf(ty1[j], py1), 0.0f);
            float inter = iw * ih;
            float iou = inter * frcp(ta[j] + pa - inter);
            if (iou > best[j]) { best[j] = iou; bestp[j] = p; }  // strict >: lowest p/lane
        }
    }
    #pragma unroll
    for (int j = 0; j < TPW; j++) {
        unsigned long long key =
            ((unsigned long long)__float_as_uint(fmaxf(best[j], 0.0f)) << 32) |
            (unsigned long long)(0xFFFFFFFFu - (unsigned)bestp[j]);
        for (int off = 32; off; off >>= 1) {
            unsigned long long k2 = __shfl_down(key, off);
            if (k2 > key) key = k2;
        }
        if (lane == 0 && bt0 + j < BT) atomicMax(&keys[bt0 + j], key);
    }
}

// ---------------- K2b: unpack keys -> u8 override map / valid bitmask / any_valid ----
__global__ void unpack_override_kernel(const unsigned long long* __restrict__ keys,
                                       int T, int BT, int P,
                                       unsigned char* __restrict__ ovr8,   // [B][P], 0=none, else t+1
                                       unsigned* __restrict__ vmask,       // [B][P/32]
                                       int* __restrict__ av_arr) {         // [B]
    int i = blockIdx.x * blockDim.x + threadIdx.x;
    if (i >= BT) return;
    unsigned long long k = keys[i];
    int bpi = (int)(0xFFFFFFFFu - (unsigned)(k & 0xFFFFFFFFull));
    float iou = __uint_as_float((unsigned)(k >> 32));
    int b = i / T, t = i % T;
    atomicMaxU8(&ovr8[(size_t)b * P + bpi], (unsigned char)(t + 1)); // last write wins == largest t
    if (iou >= VALID_THRESH) {
        atomicOr(&vmask[(size_t)b * (P >> 5) + (bpi >> 5)], 1u << (bpi & 31));
        atomicOr(&av_arr[b], 1);
    }
}

// ---------------- K3a: pure IoU argmax over T truths, PPT priors/thread --------------
__global__ void iou_scan_kernel(const float* __restrict__ priors,
                                const float* __restrict__ targets,
                                int P, int T,
                                float* __restrict__ biou,
                                unsigned char* __restrict__ bt8) {
    int b   = blockIdx.y;
    int tid = threadIdx.x;
    int p0  = (blockIdx.x * blockDim.x + tid) * PPT;

    __shared__ float4 s_box[TMAX];
    __shared__ float  s_ba[TMAX];
    if (tid < T) {
        const float* tg = targets + ((size_t)b * T + tid) * 15;
        float x1 = tg[0], y1 = tg[1], x2 = tg[2], y2 = tg[3];
        s_box[tid] = make_float4(x1, y1, x2, y2);
        s_ba[tid]  = (x2 - x1) * (y2 - y1);
    }
    __syncthreads();

    float px1[PPT], py1[PPT], px2[PPT], py2[PPT], pa[PPT];
    float best[PPT]; int btidx[PPT];
    #pragma unroll
    for (int j = 0; j < PPT; j++) {
        int p = min(p0 + j, P - 1);
        float4 pr = ((const float4*)priors)[p];
        float hw = pr.z * 0.5f, hh = pr.w * 0.5f;
        px1[j] = pr.x - hw; py1[j] = pr.y - hh;
        px2[j] = pr.x + hw; py2[j] = pr.y + hh;
        pa[j]  = (px2[j] - px1[j]) * (py2[j] - py1[j]);
        best[j] = -1.0f; btidx[j] = 0;
    }

    #pragma unroll 8
    for (int t = 0; t < T; t++) {
        float4 box = s_box[t];
        float  ba  = s_ba[t];
        #pragma unroll
        for (int j = 0; j < PPT; j++) {
            float iw = fmaxf(fminf(box.z, px2[j]) - fmaxf(box.x, px1[j]), 0.0f);
            float ih = fmaxf(fminf(box.w, py2[j]) - fmaxf(box.y, py1[j]), 0.0f);
            float inter = iw * ih;
            float iou = inter * frcp(ba + pa[j] - inter);
            if (iou > best[j]) { best[j] = iou; btidx[j] = t; }   // first occurrence
        }
    }

    if (p0 + PPT <= P) {
        *(float4*)&biou[(size_t)b * P + p0] = make_float4(best[0], best[1], best[2], best[3]);
        uchar4 bt4 = make_uchar4((unsigned char)btidx[0], (unsigned char)btidx[1],
                                 (unsigned char)btidx[2], (unsigned char)btidx[3]);
        *(uchar4*)&bt8[(size_t)b * P + p0] = bt4;
    } else {
        for (int j = 0; j < PPT; j++)
            if (p0 + j < P) {
                biou[(size_t)b * P + p0 + j] = best[j];
                bt8[(size_t)b * P + p0 + j] = (unsigned char)btidx[j];
            }
    }
}

// ---------------- K3b: streaming loss eval, EPT priors/thread, amortized hist --------
__global__ void loss_eval_kernel(const float* __restrict__ priors,
                                 const float* __restrict__ targets,
                                 const float* __restrict__ loc_data,
                                 const float* __restrict__ conf_data,
                                 const float* __restrict__ landm_data,
                                 const float* __restrict__ biou,
                                 const unsigned char* __restrict__ bt8,
                                 const unsigned char* __restrict__ ovr8,
                                 const unsigned* __restrict__ vmask,
                                 const int* __restrict__ av_arr,
                                 int P, int T,
                                 float* __restrict__ rank_loss,
                                 int* __restrict__ ghist,      // [B][HB]
                                 int* __restrict__ num_pos,    // [B]
                                 int* __restrict__ num_pos1,   // [B]
                                 float* __restrict__ accb)     // [B][3]: ll, llm, ce_pos
{
    int b   = blockIdx.y;
    int tid = threadIdx.x;
    int p0  = (blockIdx.x * blockDim.x + tid) * EPT;
    size_t base = (size_t)b * P + p0;

    __shared__ int   s_hist[HB][NC];
    __shared__ float s_ll, s_llm, s_cep;
    __shared__ int   s_np, s_np1;

    if (tid == 0) { s_ll = 0.f; s_llm = 0.f; s_cep = 0.f; s_np = 0; s_np1 = 0; }
    for (int i = tid; i < HB; i += blockDim.x)
        *(int4*)&s_hist[i][0] = make_int4(0, 0, 0, 0);
    __syncthreads();

    int hc = tid & (NC - 1);
    int av = av_arr[b];
    float ll_s = 0.f, cep_s = 0.f, llm_s = 0.f;
    int np_s = 0, np1_s = 0;

    if (p0 + EPT <= P) {
        // vector loads for 4 consecutive priors
        float bi[EPT];  *(float4*)bi = *(const float4*)&biou[base];
        unsigned bt4 = *(const unsigned*)&bt8[base];
        unsigned ov4 = *(const unsigned*)&ovr8[base];
        unsigned vb  = vmask[(size_t)b * (P >> 5) + (p0 >> 5)] >> (p0 & 31);
        float cc[2 * EPT];
        *(float4*)&cc[0] = ((const float4*)(conf_data + base * 2))[0];
        *(float4*)&cc[4] = ((const float4*)(conf_data + base * 2))[1];

        float rl[EPT];
        int   btv[EPT]; float bvv[EPT]; float cev[EPT]; int posv[EPT];
        #pragma unroll
        for (int j = 0; j < EPT; j++) {
            int bt = (bt4 >> (8 * j)) & 0xFF;
            int ov = (ov4 >> (8 * j)) & 0xFF;
            if (ov) bt = ov - 1;
            float bv = bi[j];
            if ((vb >> j) & 1u) bv = 2.0f;
            btv[j] = bt; bvv[j] = bv;

            bool cond = (av && bv >= OVERLAP_THRESH);
            // label==1 for all targets in this data ONLY via tg[14]; must gather
            float lab = cond ? targets[((size_t)b * T + bt) * 15 + 14] : 0.0f;
            int   ci  = (int)lab;
            bool  pos = cond && (ci != 0);
            posv[j] = pos;

            float c0 = cc[2 * j], c1 = cc[2 * j + 1];
            float mx = fmaxf(c0, c1);
            float lse = mx + __logf(1.0f + __expf(-fabsf(c0 - c1)));
            float ce  = lse - (pos ? c1 : c0);
            cev[j] = ce;
            rl[j] = pos ? 0.0f : fmaxf(ce, 0.0f);
            atomicAdd(&s_hist[__float_as_uint(rl[j]) >> 20][hc], 1);
        }
        *(float4*)&rank_loss[base] = *(float4*)rl;

        #pragma unroll
        for (int j = 0; j < EPT; j++) {
            if (!posv[j]) continue;
            int p = p0 + j, bt = btv[j];
            size_t idx = base + j;
            const float* tg = targets + ((size_t)b * T + bt) * 15;
            float lab = tg[14];
            bool pos1 = ((int)lab > 0);
            float4 pr = ((const float4*)priors)[p];

            float gx = ((tg[0] + tg[2]) * 0.5f - pr.x) * frcp(0.1f * pr.z);
            float gy = ((tg[1] + tg[3]) * 0.5f - pr.y) * frcp(0.1f * pr.w);
            float gw = __logf((tg[2] - tg[0]) * frcp(pr.z)) * 5.0f;
            float gh = __logf((tg[3] - tg[1]) * frcp(pr.w)) * 5.0f;
            const float* ld = loc_data + idx * 4;
            ll_s += sl1(ld[0] - gx) + sl1(ld[1] - gy) + sl1(ld[2] - gw) + sl1(ld[3] - gh);
            cep_s += cev[j];
            np_s++;

            if (pos1) {
                const float* lmd = landm_data + idx * 10;
                const float* lm  = tg + 4;
                float sx = frcp(0.1f * pr.z), sy = frcp(0.1f * pr.w);
                float s = 0.0f;
                #pragma unroll
                for (int k = 0; k < 5; k++) {
                    float gxl = (lm[2 * k]     - pr.x) * sx;
                    float gyl = (lm[2 * k + 1] - pr.y) * sy;
                    s += sl1(lmd[2 * k] - gxl) + sl1(lmd[2 * k + 1] - gyl);
                }
                llm_s += s;
                np1_s++;
            }
        }
    }

    if (np_s)  { atomicAdd(&s_ll, ll_s); atomicAdd(&s_cep, cep_s); atomicAdd(&s_np, np_s); }
    if (np1_s) { atomicAdd(&s_llm, llm_s); atomicAdd(&s_np1, np1_s); }
    __syncthreads();
    if (tid == 0) {
        if (s_np)  { atomicAdd(&num_pos[b], s_np);
                     atomicAdd(&accb[b * 3 + 0], s_ll);
                     atomicAdd(&accb[b * 3 + 2], s_cep); }
        if (s_np1) { atomicAdd(&num_pos1[b], s_np1);
                     atomicAdd(&accb[b * 3 + 1], s_llm); }
    }
    for (int i = tid; i < HB; i += blockDim.x) {
        int4 v4 = *(int4*)&s_hist[i][0];
        int v = v4.x + v4.y + v4.z + v4.w;
        if (v) atomicAdd(&ghist[(size_t)b * HB + i], v);
    }
}

// ---- single-wave digit select over nb (<=256) buckets in LDS hist ----
__device__ __forceinline__ void select_digit(const int* hist, int nb, int tid,
                                             int* s_dig, int* s_r) {
    if (tid < 64) {
        int lane = tid;
        int per  = (nb >= 64) ? (nb >> 6) : 1;
        int base = lane * per;
        int v[4]; int s = 0;
        #pragma unroll
        for (int j = 0; j < 4; j++) {
            int idx = base + j;
            int h = (j < per && idx < nb) ? hist[idx] : 0;
            v[j] = h; s += h;
        }
        int sfx = s;
        for (int off = 1; off < 64; off <<= 1) {
            int t = __shfl_down(sfx, off);
            if (lane + off < 64) sfx += t;
        }
        int r  = *s_r;
        int ge = sfx;
        #pragma unroll
        for (int j = 0; j < 4; j++) {
            int gen = ge - v[j];
            int d   = base + j;
            if (j < per && d < nb && ge >= r && gen < r) { *s_dig = d; *s_r = r - gen; }
            ge = gen;
        }
    }
}

// ---------------- K4: per-batch sum of top-K rank_loss --------------------------------
__global__ void topk_kernel(const float* __restrict__ rank_loss,
                            const int* __restrict__ num_pos,
                            const int* __restrict__ ghist,
                            int P, float* __restrict__ accn) {   // [B]
    int b    = blockIdx.x;
    int tid  = threadIdx.x;
    int lane = tid & 63;
    int wv   = tid >> 6;
    long long Kll = (long long)num_pos[b] * NEGPOS;
    int K = (Kll > P - 1) ? (P - 1) : (int)Kll;
    if (K <= 0) return;

    __shared__ int   hist[256];
    __shared__ float slist[CAP];
    __shared__ int   s_d1, s_r, s_cnt1, s_lcnt, s_dig;
    __shared__ float s_S[16];
    __shared__ int   s_C[16];
    __shared__ float s_Shi;
    __shared__ int   s_Chi;

    const int* gh = ghist + (size_t)b * HB;

    if (wv == 0) {
        if (lane == 0) { s_lcnt = 0; s_r = K; }
        int base = lane * 32;
        int v[32]; int s = 0;
        #pragma unroll
        for (int j = 0; j < 32; j++) { v[j] = gh[base + j]; s += v[j]; }
        int sfx = s;
        for (int off = 1; off < 64; off <<= 1) {
            int t = __shfl_down(sfx, off);
            if (lane + off < 64) sfx += t;
        }
        int ge = sfx;
        #pragma unroll
        for (int j = 0; j < 32; j++) {
            int gen = ge - v[j];
            if (ge >= K && gen < K) { s_d1 = base + j; s_r = K - gen; s_cnt1 = v[j]; }
            ge = gen;
        }
    }
    __syncthreads();
    int d1 = s_d1, cnt1 = s_cnt1;
    bool fastpath = (cnt1 <= CAP);
    unsigned hi_lim = ((unsigned)(d1 + 1)) << 20;

    const float4* v4 = (const float4*)(rank_loss + (size_t)b * P);
    int n4 = P >> 2;
    unsigned pmask = 0u, pval = 0u;
    const int shf[3] = {12, 4, 0};
    const int nbk[3] = {256, 256, 16};

    if (fastpath) {
        float Shi = 0.f; int Chi = 0;
        for (int i = tid; i < n4; i += blockDim.x) {
            float4 x = v4[i];
            float xs[4] = {x.x, x.y, x.z, x.w};
            #pragma unroll
            for (int k = 0; k < 4; k++) {
                unsigned u = __float_as_uint(xs[k]);
                if (u >= hi_lim) { Shi += xs[k]; Chi++; }
                bool m = ((u >> 20) == (unsigned)d1);
                unsigned long long mk = __ballot(m);
                if (m) {
                    int leader = __ffsll((long long)mk) - 1;
                    int base = 0;
                    if (lane == leader) base = atomicAdd(&s_lcnt, __popcll(mk));
                    base = __shfl(base, leader);
                    int ofs = __popcll(mk & (((unsigned long long)1 << lane) - 1ull));
                    slist[base + ofs] = xs[k];
                }
            }
        }
        for (int off = 32; off; off >>= 1) {
            Shi += __shfl_down(Shi, off);
            Chi += __shfl_down(Chi, off);
        }
        if (lane == 0) { s_S[wv] = Shi; s_C[wv] = Chi; }
        __syncthreads();
        if (tid == 0) {
            float S = 0.f; int C = 0;
            for (int i = 0; i < 16; i++) { S += s_S[i]; C += s_C[i]; }
            s_Shi = S; s_Chi = C;
        }
        __syncthreads();
        int lc = s_lcnt;

        for (int ps = 0; ps < 3; ps++) {
            int sh = shf[ps]; unsigned wm = (unsigned)(nbk[ps] - 1);
            if (tid < 256) hist[tid] = 0;
            __syncthreads();
            for (int i = tid; i < lc; i += blockDim.x) {
                unsigned u = __float_as_uint(slist[i]);
                if ((u & pmask) == pval) atomicAdd(&hist[(u >> sh) & wm], 1);
            }
            __syncthreads();
            select_digit(hist, nbk[ps], tid, &s_dig, &s_r);
            __syncthreads();
            pval  |= ((unsigned)s_dig) << sh;
            pmask |= wm << sh;
        }
        float tau = __uint_as_float((((unsigned)d1) << 20) | pval);

        float S = 0.f; int C = 0;
        for (int i = tid; i < lc; i += blockDim.x) {
            float x = slist[i];
            if (x > tau) { S += x; C++; }
        }
        for (int off = 32; off; off >>= 1) {
            S += __shfl_down(S, off);
            C += __shfl_down(C, off);
        }
        if (lane == 0) { s_S[wv] = S; s_C[wv] = C; }
        __syncthreads();
        if (tid == 0) {
            float St = s_Shi; int Ct = s_Chi;
            for (int i = 0; i < 16; i++) { St += s_S[i]; Ct += s_C[i]; }
            accn[b] = St + (float)(K - Ct) * tau;     // single writer per b
        }
    } else {
        for (int ps = 0; ps < 3; ps++) {
            int sh = shf[ps]; unsigned wm = (unsigned)(nbk[ps] - 1);
            if (tid < 256) hist[tid] = 0;
            __syncthreads();
            for (int i = tid; i < n4; i += blockDim.x) {
                float4 x = v4[i];
                float xs[4] = {x.x, x.y, x.z, x.w};
                #pragma unroll
                for (int k = 0; k < 4; k++) {
                    unsigned u = __float_as_uint(xs[k]);
                    if ((u >> 20) == (unsigned)d1 && (u & pmask) == pval)
                        atomicAdd(&hist[(u >> sh) & wm], 1);
                }
            }
            __syncthreads();
            select_digit(hist, nbk[ps], tid, &s_dig, &s_r);
            __syncthreads();
            pval  |= ((unsigned)s_dig) << sh;
            pmask |= wm << sh;
        }
        float tau = __uint_as_float((((unsigned)d1) << 20) | pval);
        float S = 0.f; int C = 0;
        for (int i = tid; i < n4; i += blockDim.x) {
            float4 x = v4[i];
            float xs[4] = {x.x, x.y, x.z, x.w};
            #pragma unroll
            for (int k = 0; k < 4; k++)
                if (xs[k] > tau) { S += xs[k]; C++; }
        }
        for (int off = 32; off; off >>= 1) {
            S += __shfl_down(S, off);
            C += __shfl_down(C, off);
        }
        if (lane == 0) { s_S[wv] = S; s_C[wv] = C; }
        __syncthreads();
        if (tid == 0) {
            float St = 0.f; int Ct = 0;
            for (int i = 0; i < 16; i++) { St += s_S[i]; Ct += s_C[i]; }
            accn[b] = St + (float)(K - Ct) * tau;
        }
    }
}

// ---------------- K5: finalize -------------------------------------------------------
__global__ void finalize_kernel(const int* __restrict__ num_pos,
                                const int* __restrict__ num_pos1,
                                const float* __restrict__ accb,
                                const float* __restrict__ accn,
                                int B, float* __restrict__ out) {
    int tp = 0, tp1 = 0;
    float ll = 0.f, llm = 0.f, cep = 0.f, cen = 0.f;
    for (int b = 0; b < B; b++) {
        tp  += num_pos[b];
        tp1 += num_pos1[b];
        ll  += accb[b * 3 + 0];
        llm += accb[b * 3 + 1];
        cep += accb[b * 3 + 2];
        cen += accn[b];
    }
    float N  = fmaxf((float)tp, 1.0f);
    float N1 = fmaxf((float)tp1, 1.0f);
    out[0] = ll / N;
    out[1] = (cep + cen) / N;
    out[2] = llm / N1;
}

extern "C" void kernel_launch(void* const* d_in, const int* in_sizes, int n_in,
                              void* d_out, int out_size, void* d_ws, size_t ws_size,
                              hipStream_t stream) {
    const float* loc_data   = (const float*)d_in[0];
    const float* conf_data  = (const float*)d_in[1];
    const float* landm_data = (const float*)d_in[2];
    const float* priors     = (const float*)d_in[3];
    const float* targets    = (const float*)d_in[4];
    float* out = (float*)d_out;

    int P  = in_sizes[3] / 4;
    int BP = in_sizes[0] / 4;
    int B  = BP / P;
    int T  = in_sizes[4] / (B * 15);
    int BT = B * T;

    char* ws = (char*)d_ws;
    float* rank_loss = (float*)ws;                    size_t off = (size_t)B * P * sizeof(float);
    float* biou      = (float*)(ws + off);            off += (size_t)B * P * sizeof(float);
    unsigned char* bt8 = (unsigned char*)(ws + off);  off += (size_t)B * P;
    // zeroed region starts here
    unsigned char* ovr8 = (unsigned char*)(ws + off); off += (size_t)B * P;
    unsigned* vmask = (unsigned*)(ws + off); off += (size_t)B * (P >> 5) * sizeof(unsigned);
    int* ghist      = (int*)(ws + off);      off += (size_t)B * HB * sizeof(int);
    unsigned long long* keys = (unsigned long long*)(ws + off); off += (size_t)BT * sizeof(unsigned long long);
    int* av_arr     = (int*)(ws + off);      off += (size_t)B * sizeof(int);
    int* num_pos    = (int*)(ws + off);      off += (size_t)B * sizeof(int);
    int* num_pos1   = (int*)(ws + off);      off += (size_t)B * sizeof(int);
    float* accb     = (float*)(ws + off);    off += (size_t)B * 3 * sizeof(float);
    float* accn     = (float*)(ws + off);    off += (size_t)B * sizeof(float);

    size_t zbytes = (size_t)((char*)(accn + B) - (char*)ovr8);
    hipMemsetAsync(ovr8, 0, zbytes, stream);

    // K2: split-K best-prior, 4 targets per wave.
    int waves   = NCHUNK * ((BT + TPW - 1) / TPW);
    int blocks2 = (waves + 3) / 4;
    best_prior_partial_kernel<<<blocks2, 256, 0, stream>>>(priors, targets, P, BT, keys);

    // K2b: unpack scatter-override map (u8 CAS-max).
    unpack_override_kernel<<<(BT + 255) / 256, 256, 0, stream>>>(keys, T, BT, P,
                                                                 ovr8, vmask, av_arr);

    // K3a: pure IoU argmax.
    dim3 ga((P + 256 * PPT - 1) / (256 * PPT), B);
    iou_scan_kernel<<<ga, 256, 0, stream>>>(priors, targets, P, T, biou, bt8);

    // K3b: streaming loss evaluation + coarse histogram (EPT priors/thread).
    dim3 gb((P + 256 * EPT - 1) / (256 * EPT), B);
    loss_eval_kernel<<<gb, 256, 0, stream>>>(priors, targets, loc_data, conf_data,
                                             landm_data, biou, bt8, ovr8, vmask, av_arr,
                                             P, T, rank_loss, ghist, num_pos, num_pos1, accb);

    // K4: top-K sum, one full scan + LDS-local refinement.
    topk_kernel<<<B, 1024, 0, stream>>>(rank_loss, num_pos, ghist, P, accn);

    finalize_kernel<<<1, 1, 0, stream>>>(num_pos, num_pos1, accb, accn, B, out);
}